// Round 5
// baseline (11.333 us; speedup 1.0000x reference)
//
#include <hip/hip_runtime.h>
#include <hip/hip_bf16.h>

// FWHT for 12 qubits (N=4096), batch 256, real/imag planes.
// out = FWHT(x) / 64  (H = (H2)^{⊗12}, entries ±1/64; H is never read).
//
// Wave-private radix-64: each 4096-vector is handled by ONE wave64.
//   round 1: FWHT-64 over bits [5:0]  (64 elems in VGPRs per lane)
//   64x64 transpose through pad-65 LDS (2 lanes/bank both phases = free)
//   round 2: FWHT-64 over bits [11:6]
// No __syncthreads-dependency between waves; 512 independent waves keep
// the memory pipe continuously busy (no phase lockstep).

#define NN 4096

__device__ __forceinline__ void fwht64(float x[64]) {
#pragma unroll
    for (int s = 0; s < 6; ++s) {
        const int st = 1 << s;
#pragma unroll
        for (int i = 0; i < 64; ++i) {
            if ((i & st) == 0) {
                const float a = x[i];
                const float b = x[i + st];
                x[i]      = a + b;
                x[i + st] = a - b;
            }
        }
    }
}

__global__ __launch_bounds__(64)
void fwht_kernel(const float* __restrict__ xr,
                 const float* __restrict__ xi,
                 float* __restrict__ out) {
    __shared__ float s[64 * 65];            // 16640 B, wave-private

    const int v = blockIdx.x;               // vector 0..511
    const int l = threadIdx.x;              // lane 0..63

    const float* src = (v < 256) ? (xr + (size_t)v * NN)
                                 : (xi + (size_t)(v - 256) * NN);
    float* dst = out + (size_t)v * NN;

    float x[64];

    // ---- load: lane l owns n = l*64 + k (16x dwordx4, lines fully used) ----
    const float4* s4 = (const float4*)(src + l * 64);
#pragma unroll
    for (int j = 0; j < 16; ++j) {
        const float4 t = s4[j];
        x[4 * j + 0] = t.x; x[4 * j + 1] = t.y;
        x[4 * j + 2] = t.z; x[4 * j + 3] = t.w;
    }

    // ---- round 1: bits [5:0] ----
    fwht64(x);

    // ---- transpose via pad-65 LDS ----
    // write row l: addr l*65+k  (lanes stride 65 -> 2/bank, free)
#pragma unroll
    for (int k = 0; k < 64; ++k)
        s[l * 65 + k] = x[k];
    __syncthreads();                        // single wave: just lgkm drain
    // read col l: addr k*65+l  (lanes stride 1 -> conflict-free)
#pragma unroll
    for (int k = 0; k < 64; ++k)
        x[k] = s[k * 65 + l];

    // ---- round 2: bits [11:6]  (lane l now owns n = k*64 + l) ----
    fwht64(x);

    // ---- scale 1/64, store: instr k writes 256B contiguous ----
    const float sc = 0.015625f;
#pragma unroll
    for (int k = 0; k < 64; ++k)
        dst[k * 64 + l] = x[k] * sc;
}

extern "C" void kernel_launch(void* const* d_in, const int* in_sizes, int n_in,
                              void* d_out, int out_size, void* d_ws, size_t ws_size,
                              hipStream_t stream) {
    const float* xr = (const float*)d_in[0];
    const float* xi = (const float*)d_in[1];
    float* out = (float*)d_out;

    fwht_kernel<<<512, 64, 0, stream>>>(xr, xi, out);
}

// Round 6
// 11.302 us; speedup vs baseline: 1.0028x; 1.0028x over previous
//
#include <hip/hip_runtime.h>
#include <hip/hip_bf16.h>

// FWHT for 12 qubits (N=4096), batch 256, real/imag planes.
// out = FWHT(x) / 64  (H = (H2)^{⊗12}, entries ±1/64; H is never read).
//
// FUSED real+imag: both planes get the identical transform, so each
// butterfly is a float2 op. One block per batch: 3 rounds total
// (vs 6 sequential in the unfused two-vector version), half the
// barriers, half the LDS instructions (b64), 2x ILP per thread.
//
// Radix-16 rounds over bits [3:0], [7:4], [11:8]; two padded-LDS
// exchanges in float2 units: n -> (n>>4)*17 + (n&15). Bank check:
// bases stride 34 dwords -> each 16-lane quarter-group covers all
// 32 banks exactly once in pairs; conflict-free.

#define NN 4096
#define T  256

__device__ __forceinline__ void fwht16c(float2 x[16]) {
#pragma unroll
    for (int s = 0; s < 4; ++s) {
        const int st = 1 << s;
#pragma unroll
        for (int i = 0; i < 16; ++i) {
            if ((i & st) == 0) {
                const float ax = x[i].x,      ay = x[i].y;
                const float bx = x[i + st].x, by = x[i + st].y;
                x[i].x      = ax + bx; x[i].y      = ay + by;
                x[i + st].x = ax - bx; x[i + st].y = ay - by;
            }
        }
    }
}

__global__ __launch_bounds__(T)
void fwht_kernel(const float* __restrict__ xr,
                 const float* __restrict__ xi,
                 float* __restrict__ out) {
    __shared__ float2 s[NN + NN / 16];      // 4352 float2 = 34 KiB

    const int b = blockIdx.x;               // batch 0..255
    const int t = threadIdx.x;              // 0..255

    const float4* pr = (const float4*)(xr + (size_t)b * NN + t * 16);
    const float4* pi = (const float4*)(xi + (size_t)b * NN + t * 16);
    float*       dr = out + (size_t)b * NN;
    float*       di = out + (size_t)(256 + b) * NN;

    // ---- load both planes (8x dwordx4/thread), zip into float2 ----
    float2 x[16];
#pragma unroll
    for (int k = 0; k < 4; ++k) {
        const float4 r = pr[k];
        const float4 i = pi[k];
        x[4 * k + 0] = make_float2(r.x, i.x);
        x[4 * k + 1] = make_float2(r.y, i.y);
        x[4 * k + 2] = make_float2(r.z, i.z);
        x[4 * k + 3] = make_float2(r.w, i.w);
    }

    // ---- Round A: bits [3:0] (thread t owns n = t*16 + r) ----
    fwht16c(x);
#pragma unroll
    for (int r = 0; r < 16; ++r)
        s[t * 17 + r] = x[r];               // addr = (n>>4)*17 + (n&15)
    __syncthreads();

    // ---- Round B: bits [7:4]; thread = (P = t>>4, R = t&15) ----
    const int baseB = (t >> 4) * 272 + (t & 15);
#pragma unroll
    for (int q = 0; q < 16; ++q) x[q] = s[baseB + q * 17];
    fwht16c(x);
#pragma unroll
    for (int q = 0; q < 16; ++q) s[baseB + q * 17] = x[q];   // same addrs
    __syncthreads();

    // ---- Round C: bits [11:8]; thread = (Q = t>>4, R = t&15) ----
    const int baseC = (t >> 4) * 17 + (t & 15);
    float2 y[16];
#pragma unroll
    for (int p = 0; p < 16; ++p) y[p] = s[baseC + p * 272];
    fwht16c(y);

    // ---- scale 1/64, store both planes (1 KiB contiguous per instr) ----
    const float sc = 0.015625f;             // (1/sqrt(2))^12
#pragma unroll
    for (int p = 0; p < 16; ++p) {
        dr[p * 256 + t] = y[p].x * sc;
        di[p * 256 + t] = y[p].y * sc;
    }
}

extern "C" void kernel_launch(void* const* d_in, const int* in_sizes, int n_in,
                              void* d_out, int out_size, void* d_ws, size_t ws_size,
                              hipStream_t stream) {
    const float* xr = (const float*)d_in[0];
    const float* xi = (const float*)d_in[1];
    float* out = (float*)d_out;

    fwht_kernel<<<256, T, 0, stream>>>(xr, xi, out);
}